// Round 14
// baseline (218.838 us; speedup 1.0000x reference)
//
#include <hip/hip_runtime.h>
#include <math.h>

#define DIM      512
#define KC       8192     // codes
#define NR       8192     // rows
#define BM       128      // rows per block
#define BN       256      // codes per tile
#define NT       4        // code tiles per block
#define CHUNK    (BN*NT)  // 1024 codes per block
#define NXB      (KC/CHUNK) // 8 partials per row
#define KT       (DIM/32) // 16 k-tiles of 32
#define EPS      0.125f   // margin below which we re-score exactly
#define MAXW     16384    // worklist capacity (>>80x expected ~200 entries)

typedef __attribute__((ext_vector_type(8))) _Float16 f16x8;
typedef __attribute__((ext_vector_type(4))) float f32x4;

#define AS1 __attribute__((address_space(1)))
#define AS3 __attribute__((address_space(3)))

// orderable key for float: monotone f -> u32
static __device__ __forceinline__ unsigned fkey(float f) {
    unsigned b = __float_as_uint(f);
    return (b & 0x80000000u) ? ~b : (b | 0x80000000u);
}

// ---------------------------------------------------------------------------
// Pack fp32 -> fp16 fragment-tiled layout, FUSED with exact e_sq (E only).
// Block = 16 rows x 512 k. Thread t: row rl=t>>4, k-tile kt=t&15 (32 k).
// e_sq: fixed-order per-thread fmaf chain + fixed shfl_xor tree -> bitwise
// deterministic across runs. Also zeroes fcount/fcount2.
// ---------------------------------------------------------------------------
__global__ void pack_kernel(const float* __restrict__ X, const float* __restrict__ E,
                            _Float16* __restrict__ Xp, _Float16* __restrict__ Ep,
                            float* __restrict__ e_sq, int* __restrict__ fcount,
                            int* __restrict__ fcount2) {
    if (blockIdx.x == 0 && blockIdx.y == 0 && threadIdx.x == 0) { *fcount = 0; *fcount2 = 0; }
    const int isE = blockIdx.y;
    const float* src = isE ? E : X;
    _Float16* dst = isE ? Ep : Xp;
    const int t  = threadIdx.x;
    const int rl = t >> 4;          // row in group 0..15
    const int kt = t & 15;          // k-tile 0..15
    const int row = blockIdx.x * 16 + rl;

    float4 v[8];
    const float4* p = reinterpret_cast<const float4*>(src + (size_t)row * DIM + kt * 32);
    #pragma unroll
    for (int q = 0; q < 8; ++q) v[q] = p[q];

    // pack: tile = row-tile * KT + kt; lane (rl + 16*kg) holds k = kg*8..+7
    _Float16* d = dst + ((size_t)blockIdx.x * 16 + kt) * 512;
    #pragma unroll
    for (int kg = 0; kg < 4; ++kg) {
        const float* vv = reinterpret_cast<const float*>(&v[kg * 2]);
        f16x8 o;
        #pragma unroll
        for (int j = 0; j < 8; ++j) o[j] = (_Float16)vv[j];
        *reinterpret_cast<f16x8*>(d + (rl + 16 * kg) * 8) = o;
    }

    if (isE) {
        const float* vv = reinterpret_cast<const float*>(v);
        float s = 0.f;
        #pragma unroll
        for (int j = 0; j < 32; ++j) s = fmaf(vv[j], vv[j], s);
        #pragma unroll
        for (int mask = 1; mask < 16; mask <<= 1) s += __shfl_xor(s, mask, 64);
        if (kt == 0) e_sq[row] = s;
    }
}

// ---------------------------------------------------------------------------
// f16 MFMA scorer — champion structure (R11/R13) with strength-reduced
// staging addresses: 4 A-tile offsets hoisted (nt-invariant), 8 B-tile
// offsets hoisted per nt, ks loop fully unrolled so every load address is
// base + compile-time koff. Hot-loop memory/sync semantics unchanged.
// ---------------------------------------------------------------------------
__global__ __launch_bounds__(256, 2)
void vq_mfma_kernel(const _Float16* __restrict__ Xp, const _Float16* __restrict__ Ep,
                    const float* __restrict__ e_sq,
                    float* __restrict__ pbest, float* __restrict__ psec,
                    int* __restrict__ pidx)
{
    // f16 elems: A tiles [0, 8192) (16 KB), B tiles [8192, 24576) (32 KB)
    __shared__ _Float16 lds[24576];   // 48 KB

    const int tid  = threadIdx.x;
    const int lane = tid & 63;
    const int w    = tid >> 6;
    const int wr   = w >> 1;          // wave row half (0/1)
    const int wc   = w & 1;           // wave col half (0/1)

    // 512 blocks = 8 chunks x 64 row-blocks; chunk = XCD id.
    const int bid = blockIdx.x;
    const int cx  = bid & 7;                // code-chunk 0..7 (= XCD)
    const int ry  = bid >> 3;               // row-block 0..63
    const int row0  = ry * BM;
    const int cbase = cx * CHUNK;
    const int rtb  = row0 >> 4;             // global row-tile base
    const int ctb0 = cbase >> 4;            // global code-tile base (nt=0)

    // ---- hoisted staging offsets (32-bit elem offsets; max < 2^23) ----
    unsigned aOff[4];                       // nt-invariant
    #pragma unroll
    for (int i = 0; i < 4; ++i) {
        const int t = w * 4 + i;
        aOff[i] = (unsigned)((((rtb + (t >> 1)) * KT + (t & 1)) << 9) + lane * 8);
    }

    float s1[16], s2[16];
    int   i1[16];
    #pragma unroll
    for (int i = 0; i < 16; ++i) { s1[i] = -INFINITY; s2[i] = -INFINITY; i1[i] = 0; }

    for (int nt = 0; nt < NT; ++nt) {
        const int code0 = cbase + nt * BN;
        const int ctb = ctb0 + nt * 16;     // 16 code row-tiles per nt

        unsigned bOff[8];                   // per-nt B staging offsets
        #pragma unroll
        for (int j = 0; j < 8; ++j) {
            const int b = w * 8 + j;
            bOff[j] = (unsigned)((((ctb + (b >> 1)) * KT + (b & 1)) << 9) + lane * 8);
        }

        f32x4 acc[4][8];
        #pragma unroll
        for (int m = 0; m < 4; ++m)
            #pragma unroll
            for (int n = 0; n < 8; ++n)
                acc[m][n] = (f32x4){0.f, 0.f, 0.f, 0.f};

        #pragma unroll
        for (int ks = 0; ks < 8; ++ks) {    // BK=64 steps, koff compile-time
            const unsigned koff = ks * 1024;   // elems = ks*2048 B
            // ---- stage: 16 A-tiles (4/wave) + 32 B-tiles (8/wave), 1 KB each
            #pragma unroll
            for (int i = 0; i < 4; ++i) {
                const int t = w * 4 + i;           // A tile 0..15
                __builtin_amdgcn_global_load_lds(
                    (const AS1 void*)(Xp + aOff[i] + koff),
                    (AS3 void*)(lds + t * 512), 16, 0, 0);
            }
            #pragma unroll
            for (int j = 0; j < 8; ++j) {
                const int b = w * 8 + j;           // B tile 0..31
                __builtin_amdgcn_global_load_lds(
                    (const AS1 void*)(Ep + bOff[j] + koff),
                    (AS3 void*)(lds + 8192 + b * 512), 16, 0, 0);
            }
            __syncthreads();

            // ---- compute: 2 kk x (12 ds_read_b128, 32 MFMA)
            #pragma unroll
            for (int kk = 0; kk < 2; ++kk) {
                f16x8 bfrag[8];
                #pragma unroll
                for (int n = 0; n < 8; ++n)
                    bfrag[n] = *reinterpret_cast<const f16x8*>(
                        lds + 8192 + ((wc * 8 + n) * 2 + kk) * 512 + lane * 8);
                #pragma unroll
                for (int m = 0; m < 4; ++m) {
                    const f16x8 afrag = *reinterpret_cast<const f16x8*>(
                        lds + ((wr * 4 + m) * 2 + kk) * 512 + lane * 8);
                    #pragma unroll
                    for (int n = 0; n < 8; ++n)
                        acc[m][n] = __builtin_amdgcn_mfma_f32_16x16x32_f16(
                            afrag, bfrag[n], acc[m][n], 0, 0, 0);
                }
            }
            __syncthreads();
        }

        // ---- fold this 256-code tile into running (best, second, idx) ----
        #pragma unroll
        for (int n = 0; n < 8; ++n) {
            const int code = code0 + wc * 128 + n * 16 + (lane & 15);
            const float esv = e_sq[code];          // L2-hot, 4x per block
            #pragma unroll
            for (int m = 0; m < 4; ++m) {
                #pragma unroll
                for (int r = 0; r < 4; ++r) {
                    const float sc = fmaf(2.0f, acc[m][n][r], -esv);
                    const int slot = m * 4 + r;
                    if (sc > s1[slot]) { s2[slot] = s1[slot]; s1[slot] = sc; i1[slot] = code; }
                    else if (sc > s2[slot]) { s2[slot] = sc; }
                    else if (sc == s1[slot]) { s2[slot] = sc; }   // exact tie -> margin 0
                }
            }
        }
    }

    // ---- cross-lane reduce within each 16-lane col group ----
    #pragma unroll
    for (int slot = 0; slot < 16; ++slot) {
        #pragma unroll
        for (int mask = 1; mask < 16; mask <<= 1) {
            float t1 = __shfl_xor(s1[slot], mask, 64);
            float t2 = __shfl_xor(s2[slot], mask, 64);
            int   j1 = __shfl_xor(i1[slot], mask, 64);
            if (t1 > s1[slot]) { s2[slot] = fmaxf(s1[slot], t2); s1[slot] = t1; i1[slot] = j1; }
            else if (t1 == s1[slot]) { s2[slot] = fmaxf(s2[slot], fmaxf(t1, t2)); i1[slot] = min(i1[slot], j1); }
            else { s2[slot] = fmaxf(s2[slot], t1); }
        }
    }

    __syncthreads();   // all compute done before aliasing LDS
    float* reds1 = reinterpret_cast<float*>(&lds[0]);     // [BM][2]
    float* reds2 = reds1 + BM * 2;                        // [BM][2]
    int*   redi  = reinterpret_cast<int*>(reds2 + BM * 2);// [BM][2]

    if ((lane & 15) == 0) {
        #pragma unroll
        for (int m = 0; m < 4; ++m)
            #pragma unroll
            for (int r = 0; r < 4; ++r) {
                const int row = wr * 64 + m * 16 + (lane >> 4) * 4 + r;
                reds1[row * 2 + wc] = s1[m * 4 + r];
                reds2[row * 2 + wc] = s2[m * 4 + r];
                redi [row * 2 + wc] = i1[m * 4 + r];
            }
    }
    __syncthreads();

    if (tid < BM) {
        float a1 = reds1[tid * 2 + 0], a2 = reds2[tid * 2 + 0]; int ai = redi[tid * 2 + 0];
        const float b1 = reds1[tid * 2 + 1], b2 = reds2[tid * 2 + 1]; const int bi = redi[tid * 2 + 1];
        if (b1 > a1)       { a2 = fmaxf(a1, b2); a1 = b1; ai = bi; }
        else if (b1 == a1) { a2 = fmaxf(a2, fmaxf(b1, b2)); ai = min(ai, bi); }
        else               { a2 = fmaxf(a2, b1); }
        const int row = row0 + tid;
        pbest[(size_t)row * NXB + cx] = a1;
        psec [(size_t)row * NXB + cx] = a2;
        pidx [(size_t)row * NXB + cx] = ai;
    }
}

// ---------------------------------------------------------------------------
// Fused reduce + gather (unchanged from R13). Wave per row; unflagged rows
// gathered immediately; flagged rows emit worklist + frow2 for fixup.
// ---------------------------------------------------------------------------
__global__ __launch_bounds__(256)
void reduce_gather_kernel(const float* __restrict__ pbest, const float* __restrict__ psec,
                          const int* __restrict__ pidx, const float* __restrict__ E,
                          int* __restrict__ final_idx,
                          int* __restrict__ fcount, int* __restrict__ wlist,
                          int* __restrict__ fcount2, int* __restrict__ frow2,
                          unsigned long long* __restrict__ rkey,
                          float* __restrict__ out_q, float* __restrict__ out_i)
{
    const int wv   = threadIdx.x >> 6;
    const int lane = threadIdx.x & 63;
    const int row  = blockIdx.x * 4 + wv;

    float t1 = -INFINITY, t2 = -INFINITY, own = -INFINITY;
    int   j1 = 0;
    if (lane < 8) {
        t1  = pbest[(size_t)row * NXB + lane];
        t2  = psec [(size_t)row * NXB + lane];
        j1  = pidx [(size_t)row * NXB + lane];
        own = t1;
    }
    #pragma unroll
    for (int mask = 1; mask < 8; mask <<= 1) {
        const float o1 = __shfl_xor(t1, mask, 64);
        const float o2 = __shfl_xor(t2, mask, 64);
        const int   oj = __shfl_xor(j1, mask, 64);
        if (o1 > t1)       { t2 = fmaxf(t1, o2); t1 = o1; j1 = oj; }
        else if (o1 == t1) { t2 = fmaxf(t2, fmaxf(o1, o2)); j1 = min(j1, oj); }
        else               { t2 = fmaxf(t2, o1); }
    }
    const int   fl = (t1 - t2 < EPS) ? 1 : 0;   // valid lanes 0-7
    const float s1 = __shfl(t1, 0, 64);
    const int   bi = __shfl(j1, 0, 64);
    const int   flag = __shfl(fl, 0, 64);

    if (flag) {
        if (lane < 8 && own >= s1 - EPS) {
            const int p = atomicAdd(fcount, 1);
            if (p < MAXW) wlist[p] = (row << 4) | lane;
        }
        if (lane == 0) {
            rkey[row] = 0ULL;
            final_idx[row] = bi;                 // fallback for fixup
            const int p2 = atomicAdd(fcount2, 1);
            if (p2 < NR) frow2[p2] = row;
        }
    } else {
        const float4* src = reinterpret_cast<const float4*>(E + (size_t)bi * DIM) + lane * 2;
        float4* dst = reinterpret_cast<float4*>(out_q + (size_t)row * DIM) + lane * 2;
        dst[0] = src[0];
        dst[1] = src[1];
        if (lane == 0) out_i[row] = (float)bi;
    }
}

// ---------------------------------------------------------------------------
// Exact fp32 rescore over worklist chunks (unchanged). Grid (1024,4).
// ---------------------------------------------------------------------------
__global__ __launch_bounds__(256)
void rescue_kernel(const float* __restrict__ X, const float* __restrict__ E,
                   const float* __restrict__ e_sq,
                   const int* __restrict__ fcount, const int* __restrict__ wlist,
                   unsigned long long* __restrict__ rkey)
{
    const int nw0 = *fcount;
    const int nw  = nw0 < MAXW ? nw0 : MAXW;
    const int lane = threadIdx.x & 63;
    const int w    = threadIdx.x >> 6;
    const int q    = blockIdx.y;            // quarter 0..3

    for (int e = blockIdx.x; e < nw; e += gridDim.x) {
        const unsigned ent = (unsigned)wlist[e];
        const int row = ent >> 4;
        const int j   = ent & 15;
        if (row >= NR || j >= NXB) continue;   // guard stale/garbage entries

        const float4* xp = reinterpret_cast<const float4*>(X + (size_t)row * DIM) + lane * 2;
        const float4 x0 = xp[0], x1 = xp[1];

        const int c0 = j * CHUNK + q * 256 + w * 64;
        float best = -INFINITY; int bi = 0;
        for (int c = c0; c < c0 + 64; ++c) {
            const float4* ep = reinterpret_cast<const float4*>(E + (size_t)c * DIM) + lane * 2;
            const float4 e0 = ep[0], e1 = ep[1];
            float dot = x0.x * e0.x;
            dot = fmaf(x0.y, e0.y, dot);
            dot = fmaf(x0.z, e0.z, dot);
            dot = fmaf(x0.w, e0.w, dot);
            dot = fmaf(x1.x, e1.x, dot);
            dot = fmaf(x1.y, e1.y, dot);
            dot = fmaf(x1.z, e1.z, dot);
            dot = fmaf(x1.w, e1.w, dot);
            #pragma unroll
            for (int mask = 1; mask < 64; mask <<= 1) dot += __shfl_xor(dot, mask, 64);
            const float s = fmaf(2.f, dot, -e_sq[c]);
            if (s > best) { best = s; bi = c; }    // ascending c: first occurrence wins
        }
        if (lane == 0) {
            const unsigned long long pk =
                ((unsigned long long)fkey(best) << 32) | (unsigned)(8191 - bi);
            atomicMax(&rkey[row], pk);
        }
    }
}

// ---------------------------------------------------------------------------
// Fixup: finish flagged rows (unpack atomicMax key, write index + gather).
// ---------------------------------------------------------------------------
__global__ __launch_bounds__(128)
void fixup_kernel(const int* __restrict__ fcount2, const int* __restrict__ frow2,
                  const unsigned long long* __restrict__ rkey,
                  const int* __restrict__ final_idx, const float* __restrict__ E,
                  float* __restrict__ out_q, float* __restrict__ out_i)
{
    const int nf0 = *fcount2;
    const int nf  = nf0 < NR ? nf0 : NR;
    for (int f = blockIdx.x; f < nf; f += gridDim.x) {
        const int row = frow2[f];
        if ((unsigned)row >= NR) continue;
        const unsigned long long pk = rkey[row];
        int bi = (pk == 0ULL) ? final_idx[row] : (8191 - (int)(pk & 0xFFFFFFFFull));
        if ((unsigned)bi >= KC) bi = 0;
        if (threadIdx.x == 0) out_i[row] = (float)bi;
        const float4* src = reinterpret_cast<const float4*>(E + (size_t)bi * DIM) + threadIdx.x;
        reinterpret_cast<float4*>(out_q + (size_t)row * DIM)[threadIdx.x] = src[0];
    }
}

// ---------------------------------------------------------------------------
extern "C" void kernel_launch(void* const* d_in, const int* in_sizes, int n_in,
                              void* d_out, int out_size, void* d_ws, size_t ws_size,
                              hipStream_t stream) {
    const float* X = (const float*)d_in[0];   // [8192, 512]
    const float* E = (const float*)d_in[1];   // [8192, 512]

    float* out_q = (float*)d_out;                         // [8192, 512]
    float* out_i = (float*)d_out + (size_t)NR * DIM;      // [8192]

    // Packed fp16 planes live in d_out's space (16 MB of 16.03 MB);
    // reduce_gather/fixup fully overwrite d_out at the end of every launch.
    _Float16* Xp = (_Float16*)d_out;                      // 8 MB
    _Float16* Ep = Xp + (size_t)NR * DIM;                 // 8 MB

    // ws layout (rkey first for 8-byte alignment)
    unsigned long long* rkey = (unsigned long long*)d_ws; // NR u64 (64 KB)
    float* e_sq      = (float*)(rkey + NR);               // 8192 f
    float* pbest     = e_sq + KC;                         // 8192*8 f
    float* psec      = pbest + (size_t)NR * NXB;          // 8192*8 f
    int*   pidx      = (int*)(psec + (size_t)NR * NXB);   // 8192*8 i
    int*   final_idx = pidx + (size_t)NR * NXB;           // 8192 i
    int*   frow2     = final_idx + NR;                    // NR i
    int*   wlist     = frow2 + NR;                        // MAXW i (64 KB)
    int*   fcount    = wlist + MAXW;                      // 1 i
    int*   fcount2   = fcount + 1;                        // 1 i

    hipLaunchKernelGGL(pack_kernel, dim3(NR / 16, 2), dim3(256), 0, stream,
                       X, E, Xp, Ep, e_sq, fcount, fcount2);

    hipLaunchKernelGGL(vq_mfma_kernel, dim3(NXB * (NR / BM)), dim3(256), 0, stream,
                       Xp, Ep, e_sq, pbest, psec, pidx);

    hipLaunchKernelGGL(reduce_gather_kernel, dim3(NR / 4), dim3(256), 0, stream,
                       pbest, psec, pidx, E, final_idx, fcount, wlist,
                       fcount2, frow2, rkey, out_q, out_i);

    hipLaunchKernelGGL(rescue_kernel, dim3(1024, 4), dim3(256), 0, stream,
                       X, E, e_sq, fcount, wlist, rkey);

    hipLaunchKernelGGL(fixup_kernel, dim3(512), dim3(128), 0, stream,
                       fcount2, frow2, rkey, final_idx, E, out_q, out_i);
}

// Round 15
// 179.692 us; speedup vs baseline: 1.2179x; 1.2179x over previous
//
#include <hip/hip_runtime.h>
#include <math.h>

#define DIM      512
#define KC       8192     // codes
#define NR       8192     // rows
#define BM       128      // rows per block
#define BN       256      // codes per tile
#define NT       4        // code tiles per block
#define CHUNK    (BN*NT)  // 1024 codes per block
#define NXB      (KC/CHUNK) // 8 partials per row
#define KT       (DIM/32) // 16 k-tiles of 32
#define EPS      0.125f   // margin below which we re-score exactly
#define MAXW     16384    // worklist capacity (>>80x expected ~200 entries)

typedef __attribute__((ext_vector_type(8))) _Float16 f16x8;
typedef __attribute__((ext_vector_type(4))) float f32x4;

#define AS1 __attribute__((address_space(1)))
#define AS3 __attribute__((address_space(3)))

// orderable key for float: monotone f -> u32
static __device__ __forceinline__ unsigned fkey(float f) {
    unsigned b = __float_as_uint(f);
    return (b & 0x80000000u) ? ~b : (b | 0x80000000u);
}

// ---------------------------------------------------------------------------
// Pack fp32 -> fp16 fragment-tiled layout, FUSED with exact e_sq (E only).
// Block = 16 rows x 512 k. Thread t: row rl=t>>4, k-tile kt=t&15 (32 k).
// e_sq: fixed-order per-thread fmaf chain + fixed shfl_xor tree -> bitwise
// deterministic across runs. Also zeroes fcount/fcount2.
// ---------------------------------------------------------------------------
__global__ void pack_kernel(const float* __restrict__ X, const float* __restrict__ E,
                            _Float16* __restrict__ Xp, _Float16* __restrict__ Ep,
                            float* __restrict__ e_sq, int* __restrict__ fcount,
                            int* __restrict__ fcount2) {
    if (blockIdx.x == 0 && blockIdx.y == 0 && threadIdx.x == 0) { *fcount = 0; *fcount2 = 0; }
    const int isE = blockIdx.y;
    const float* src = isE ? E : X;
    _Float16* dst = isE ? Ep : Xp;
    const int t  = threadIdx.x;
    const int rl = t >> 4;          // row in group 0..15
    const int kt = t & 15;          // k-tile 0..15
    const int row = blockIdx.x * 16 + rl;

    float4 v[8];
    const float4* p = reinterpret_cast<const float4*>(src + (size_t)row * DIM + kt * 32);
    #pragma unroll
    for (int q = 0; q < 8; ++q) v[q] = p[q];

    // pack: tile = row-tile * KT + kt; lane (rl + 16*kg) holds k = kg*8..+7
    _Float16* d = dst + ((size_t)blockIdx.x * 16 + kt) * 512;
    #pragma unroll
    for (int kg = 0; kg < 4; ++kg) {
        const float* vv = reinterpret_cast<const float*>(&v[kg * 2]);
        f16x8 o;
        #pragma unroll
        for (int j = 0; j < 8; ++j) o[j] = (_Float16)vv[j];
        *reinterpret_cast<f16x8*>(d + (rl + 16 * kg) * 8) = o;
    }

    if (isE) {
        const float* vv = reinterpret_cast<const float*>(v);
        float s = 0.f;
        #pragma unroll
        for (int j = 0; j < 32; ++j) s = fmaf(vv[j], vv[j], s);
        #pragma unroll
        for (int mask = 1; mask < 16; mask <<= 1) s += __shfl_xor(s, mask, 64);
        if (kt == 0) e_sq[row] = s;
    }
}

// ---------------------------------------------------------------------------
// f16 MFMA scorer — champion config (R11/R13 structure, runtime address
// computation — the 8x-unrolled variant thrashed I-cache, ERRATA R14).
// Single variable this round: s_setprio(1) around the compute phase. The 2
// independent blocks/CU are at different phases (stage vs compute), so the
// CU scheduler has role diversity to arbitrate (T5 mechanism).
// ---------------------------------------------------------------------------
__global__ __launch_bounds__(256, 2)
void vq_mfma_kernel(const _Float16* __restrict__ Xp, const _Float16* __restrict__ Ep,
                    const float* __restrict__ e_sq,
                    float* __restrict__ pbest, float* __restrict__ psec,
                    int* __restrict__ pidx)
{
    // f16 elems: A tiles [0, 8192) (16 KB), B tiles [8192, 24576) (32 KB)
    __shared__ _Float16 lds[24576];   // 48 KB

    const int tid  = threadIdx.x;
    const int lane = tid & 63;
    const int w    = tid >> 6;
    const int wr   = w >> 1;          // wave row half (0/1)
    const int wc   = w & 1;           // wave col half (0/1)

    // 512 blocks = 8 chunks x 64 row-blocks; chunk = XCD id.
    const int bid = blockIdx.x;
    const int cx  = bid & 7;                // code-chunk 0..7 (= XCD)
    const int ry  = bid >> 3;               // row-block 0..63
    const int row0  = ry * BM;
    const int cbase = cx * CHUNK;
    const int rtb  = row0 >> 4;             // global row-tile base
    const int ctb0 = cbase >> 4;            // global code-tile base (nt=0)

    float s1[16], s2[16];
    int   i1[16];
    #pragma unroll
    for (int i = 0; i < 16; ++i) { s1[i] = -INFINITY; s2[i] = -INFINITY; i1[i] = 0; }

    for (int nt = 0; nt < NT; ++nt) {
        const int code0 = cbase + nt * BN;
        const int ctb = ctb0 + nt * 16;     // 16 code row-tiles per nt

        f32x4 acc[4][8];
        #pragma unroll
        for (int m = 0; m < 4; ++m)
            #pragma unroll
            for (int n = 0; n < 8; ++n)
                acc[m][n] = (f32x4){0.f, 0.f, 0.f, 0.f};

        for (int ks = 0; ks < 8; ++ks) {    // BK=64 steps
            const int kt2 = ks * 2;
            // ---- stage: 16 A-tiles (4/wave) + 32 B-tiles (8/wave), 1 KB each
            #pragma unroll
            for (int i = 0; i < 4; ++i) {
                const int t = w * 4 + i;           // A tile 0..15
                const int rt = t >> 1, ktl = t & 1;
                const _Float16* gp = Xp + (((size_t)(rtb + rt) * KT + kt2 + ktl) << 9) + lane * 8;
                __builtin_amdgcn_global_load_lds(
                    (const AS1 void*)gp, (AS3 void*)(lds + t * 512), 16, 0, 0);
            }
            #pragma unroll
            for (int j = 0; j < 8; ++j) {
                const int b = w * 8 + j;           // B tile 0..31
                const int rt = b >> 1, ktl = b & 1;
                const _Float16* gp = Ep + (((size_t)(ctb + rt) * KT + kt2 + ktl) << 9) + lane * 8;
                __builtin_amdgcn_global_load_lds(
                    (const AS1 void*)gp, (AS3 void*)(lds + 8192 + b * 512), 16, 0, 0);
            }
            __syncthreads();

            // ---- compute: 2 kk x (12 ds_read_b128, 32 MFMA), prioritized
            __builtin_amdgcn_s_setprio(1);
            #pragma unroll
            for (int kk = 0; kk < 2; ++kk) {
                f16x8 bfrag[8];
                #pragma unroll
                for (int n = 0; n < 8; ++n)
                    bfrag[n] = *reinterpret_cast<const f16x8*>(
                        lds + 8192 + ((wc * 8 + n) * 2 + kk) * 512 + lane * 8);
                #pragma unroll
                for (int m = 0; m < 4; ++m) {
                    const f16x8 afrag = *reinterpret_cast<const f16x8*>(
                        lds + ((wr * 4 + m) * 2 + kk) * 512 + lane * 8);
                    #pragma unroll
                    for (int n = 0; n < 8; ++n)
                        acc[m][n] = __builtin_amdgcn_mfma_f32_16x16x32_f16(
                            afrag, bfrag[n], acc[m][n], 0, 0, 0);
                }
            }
            __builtin_amdgcn_s_setprio(0);
            __syncthreads();
        }

        // ---- fold this 256-code tile into running (best, second, idx) ----
        #pragma unroll
        for (int n = 0; n < 8; ++n) {
            const int code = code0 + wc * 128 + n * 16 + (lane & 15);
            const float esv = e_sq[code];          // L2-hot, 4x per block
            #pragma unroll
            for (int m = 0; m < 4; ++m) {
                #pragma unroll
                for (int r = 0; r < 4; ++r) {
                    const float sc = fmaf(2.0f, acc[m][n][r], -esv);
                    const int slot = m * 4 + r;
                    if (sc > s1[slot]) { s2[slot] = s1[slot]; s1[slot] = sc; i1[slot] = code; }
                    else if (sc > s2[slot]) { s2[slot] = sc; }
                    else if (sc == s1[slot]) { s2[slot] = sc; }   // exact tie -> margin 0
                }
            }
        }
    }

    // ---- cross-lane reduce within each 16-lane col group ----
    #pragma unroll
    for (int slot = 0; slot < 16; ++slot) {
        #pragma unroll
        for (int mask = 1; mask < 16; mask <<= 1) {
            float t1 = __shfl_xor(s1[slot], mask, 64);
            float t2 = __shfl_xor(s2[slot], mask, 64);
            int   j1 = __shfl_xor(i1[slot], mask, 64);
            if (t1 > s1[slot]) { s2[slot] = fmaxf(s1[slot], t2); s1[slot] = t1; i1[slot] = j1; }
            else if (t1 == s1[slot]) { s2[slot] = fmaxf(s2[slot], fmaxf(t1, t2)); i1[slot] = min(i1[slot], j1); }
            else { s2[slot] = fmaxf(s2[slot], t1); }
        }
    }

    __syncthreads();   // all compute done before aliasing LDS
    float* reds1 = reinterpret_cast<float*>(&lds[0]);     // [BM][2]
    float* reds2 = reds1 + BM * 2;                        // [BM][2]
    int*   redi  = reinterpret_cast<int*>(reds2 + BM * 2);// [BM][2]

    if ((lane & 15) == 0) {
        #pragma unroll
        for (int m = 0; m < 4; ++m)
            #pragma unroll
            for (int r = 0; r < 4; ++r) {
                const int row = wr * 64 + m * 16 + (lane >> 4) * 4 + r;
                reds1[row * 2 + wc] = s1[m * 4 + r];
                reds2[row * 2 + wc] = s2[m * 4 + r];
                redi [row * 2 + wc] = i1[m * 4 + r];
            }
    }
    __syncthreads();

    if (tid < BM) {
        float a1 = reds1[tid * 2 + 0], a2 = reds2[tid * 2 + 0]; int ai = redi[tid * 2 + 0];
        const float b1 = reds1[tid * 2 + 1], b2 = reds2[tid * 2 + 1]; const int bi = redi[tid * 2 + 1];
        if (b1 > a1)       { a2 = fmaxf(a1, b2); a1 = b1; ai = bi; }
        else if (b1 == a1) { a2 = fmaxf(a2, fmaxf(b1, b2)); ai = min(ai, bi); }
        else               { a2 = fmaxf(a2, b1); }
        const int row = row0 + tid;
        pbest[(size_t)row * NXB + cx] = a1;
        psec [(size_t)row * NXB + cx] = a2;
        pidx [(size_t)row * NXB + cx] = ai;
    }
}

// ---------------------------------------------------------------------------
// Fused reduce + gather (unchanged). Wave per row; unflagged rows gathered
// immediately; flagged rows emit worklist + frow2 for fixup.
// ---------------------------------------------------------------------------
__global__ __launch_bounds__(256)
void reduce_gather_kernel(const float* __restrict__ pbest, const float* __restrict__ psec,
                          const int* __restrict__ pidx, const float* __restrict__ E,
                          int* __restrict__ final_idx,
                          int* __restrict__ fcount, int* __restrict__ wlist,
                          int* __restrict__ fcount2, int* __restrict__ frow2,
                          unsigned long long* __restrict__ rkey,
                          float* __restrict__ out_q, float* __restrict__ out_i)
{
    const int wv   = threadIdx.x >> 6;
    const int lane = threadIdx.x & 63;
    const int row  = blockIdx.x * 4 + wv;

    float t1 = -INFINITY, t2 = -INFINITY, own = -INFINITY;
    int   j1 = 0;
    if (lane < 8) {
        t1  = pbest[(size_t)row * NXB + lane];
        t2  = psec [(size_t)row * NXB + lane];
        j1  = pidx [(size_t)row * NXB + lane];
        own = t1;
    }
    #pragma unroll
    for (int mask = 1; mask < 8; mask <<= 1) {
        const float o1 = __shfl_xor(t1, mask, 64);
        const float o2 = __shfl_xor(t2, mask, 64);
        const int   oj = __shfl_xor(j1, mask, 64);
        if (o1 > t1)       { t2 = fmaxf(t1, o2); t1 = o1; j1 = oj; }
        else if (o1 == t1) { t2 = fmaxf(t2, fmaxf(o1, o2)); j1 = min(j1, oj); }
        else               { t2 = fmaxf(t2, o1); }
    }
    const int   fl = (t1 - t2 < EPS) ? 1 : 0;   // valid lanes 0-7
    const float s1 = __shfl(t1, 0, 64);
    const int   bi = __shfl(j1, 0, 64);
    const int   flag = __shfl(fl, 0, 64);

    if (flag) {
        if (lane < 8 && own >= s1 - EPS) {
            const int p = atomicAdd(fcount, 1);
            if (p < MAXW) wlist[p] = (row << 4) | lane;
        }
        if (lane == 0) {
            rkey[row] = 0ULL;
            final_idx[row] = bi;                 // fallback for fixup
            const int p2 = atomicAdd(fcount2, 1);
            if (p2 < NR) frow2[p2] = row;
        }
    } else {
        const float4* src = reinterpret_cast<const float4*>(E + (size_t)bi * DIM) + lane * 2;
        float4* dst = reinterpret_cast<float4*>(out_q + (size_t)row * DIM) + lane * 2;
        dst[0] = src[0];
        dst[1] = src[1];
        if (lane == 0) out_i[row] = (float)bi;
    }
}

// ---------------------------------------------------------------------------
// Exact fp32 rescore over worklist chunks (unchanged). Grid (1024,4).
// ---------------------------------------------------------------------------
__global__ __launch_bounds__(256)
void rescue_kernel(const float* __restrict__ X, const float* __restrict__ E,
                   const float* __restrict__ e_sq,
                   const int* __restrict__ fcount, const int* __restrict__ wlist,
                   unsigned long long* __restrict__ rkey)
{
    const int nw0 = *fcount;
    const int nw  = nw0 < MAXW ? nw0 : MAXW;
    const int lane = threadIdx.x & 63;
    const int w    = threadIdx.x >> 6;
    const int q    = blockIdx.y;            // quarter 0..3

    for (int e = blockIdx.x; e < nw; e += gridDim.x) {
        const unsigned ent = (unsigned)wlist[e];
        const int row = ent >> 4;
        const int j   = ent & 15;
        if (row >= NR || j >= NXB) continue;   // guard stale/garbage entries

        const float4* xp = reinterpret_cast<const float4*>(X + (size_t)row * DIM) + lane * 2;
        const float4 x0 = xp[0], x1 = xp[1];

        const int c0 = j * CHUNK + q * 256 + w * 64;
        float best = -INFINITY; int bi = 0;
        for (int c = c0; c < c0 + 64; ++c) {
            const float4* ep = reinterpret_cast<const float4*>(E + (size_t)c * DIM) + lane * 2;
            const float4 e0 = ep[0], e1 = ep[1];
            float dot = x0.x * e0.x;
            dot = fmaf(x0.y, e0.y, dot);
            dot = fmaf(x0.z, e0.z, dot);
            dot = fmaf(x0.w, e0.w, dot);
            dot = fmaf(x1.x, e1.x, dot);
            dot = fmaf(x1.y, e1.y, dot);
            dot = fmaf(x1.z, e1.z, dot);
            dot = fmaf(x1.w, e1.w, dot);
            #pragma unroll
            for (int mask = 1; mask < 64; mask <<= 1) dot += __shfl_xor(dot, mask, 64);
            const float s = fmaf(2.f, dot, -e_sq[c]);
            if (s > best) { best = s; bi = c; }    // ascending c: first occurrence wins
        }
        if (lane == 0) {
            const unsigned long long pk =
                ((unsigned long long)fkey(best) << 32) | (unsigned)(8191 - bi);
            atomicMax(&rkey[row], pk);
        }
    }
}

// ---------------------------------------------------------------------------
// Fixup: finish flagged rows (unpack atomicMax key, write index + gather).
// ---------------------------------------------------------------------------
__global__ __launch_bounds__(128)
void fixup_kernel(const int* __restrict__ fcount2, const int* __restrict__ frow2,
                  const unsigned long long* __restrict__ rkey,
                  const int* __restrict__ final_idx, const float* __restrict__ E,
                  float* __restrict__ out_q, float* __restrict__ out_i)
{
    const int nf0 = *fcount2;
    const int nf  = nf0 < NR ? nf0 : NR;
    for (int f = blockIdx.x; f < nf; f += gridDim.x) {
        const int row = frow2[f];
        if ((unsigned)row >= NR) continue;
        const unsigned long long pk = rkey[row];
        int bi = (pk == 0ULL) ? final_idx[row] : (8191 - (int)(pk & 0xFFFFFFFFull));
        if ((unsigned)bi >= KC) bi = 0;
        if (threadIdx.x == 0) out_i[row] = (float)bi;
        const float4* src = reinterpret_cast<const float4*>(E + (size_t)bi * DIM) + threadIdx.x;
        reinterpret_cast<float4*>(out_q + (size_t)row * DIM)[threadIdx.x] = src[0];
    }
}

// ---------------------------------------------------------------------------
extern "C" void kernel_launch(void* const* d_in, const int* in_sizes, int n_in,
                              void* d_out, int out_size, void* d_ws, size_t ws_size,
                              hipStream_t stream) {
    const float* X = (const float*)d_in[0];   // [8192, 512]
    const float* E = (const float*)d_in[1];   // [8192, 512]

    float* out_q = (float*)d_out;                         // [8192, 512]
    float* out_i = (float*)d_out + (size_t)NR * DIM;      // [8192]

    // Packed fp16 planes live in d_out's space (16 MB of 16.03 MB);
    // reduce_gather/fixup fully overwrite d_out at the end of every launch.
    _Float16* Xp = (_Float16*)d_out;                      // 8 MB
    _Float16* Ep = Xp + (size_t)NR * DIM;                 // 8 MB

    // ws layout (rkey first for 8-byte alignment)
    unsigned long long* rkey = (unsigned long long*)d_ws; // NR u64 (64 KB)
    float* e_sq      = (float*)(rkey + NR);               // 8192 f
    float* pbest     = e_sq + KC;                         // 8192*8 f
    float* psec      = pbest + (size_t)NR * NXB;          // 8192*8 f
    int*   pidx      = (int*)(psec + (size_t)NR * NXB);   // 8192*8 i
    int*   final_idx = pidx + (size_t)NR * NXB;           // 8192 i
    int*   frow2     = final_idx + NR;                    // NR i
    int*   wlist     = frow2 + NR;                        // MAXW i (64 KB)
    int*   fcount    = wlist + MAXW;                      // 1 i
    int*   fcount2   = fcount + 1;                        // 1 i

    hipLaunchKernelGGL(pack_kernel, dim3(NR / 16, 2), dim3(256), 0, stream,
                       X, E, Xp, Ep, e_sq, fcount, fcount2);

    hipLaunchKernelGGL(vq_mfma_kernel, dim3(NXB * (NR / BM)), dim3(256), 0, stream,
                       Xp, Ep, e_sq, pbest, psec, pidx);

    hipLaunchKernelGGL(reduce_gather_kernel, dim3(NR / 4), dim3(256), 0, stream,
                       pbest, psec, pidx, E, final_idx, fcount, wlist,
                       fcount2, frow2, rkey, out_q, out_i);

    hipLaunchKernelGGL(rescue_kernel, dim3(1024, 4), dim3(256), 0, stream,
                       X, E, e_sq, fcount, wlist, rkey);

    hipLaunchKernelGGL(fixup_kernel, dim3(512), dim3(128), 0, stream,
                       fcount2, frow2, rkey, final_idx, E, out_q, out_i);
}